// Round 16
// baseline (1175.915 us; speedup 1.0000x reference)
//
#include <hip/hip_runtime.h>
#include <hip/hip_bf16.h>
#include <math.h>

#define NPTS 100000
#define PAD_ROWS 100096   // 782 * 128 = 1564 * 64
#define DIM 512
#define GRP 4
#define GD 128
#define K_NBR 16
#define EPS 1e-5f

using bf16x8 = __attribute__((ext_vector_type(8))) short;
using f32x4  = __attribute__((ext_vector_type(4))) float;
using short4v = __attribute__((ext_vector_type(4))) short;

__device__ inline float bf2f(short s) {
    unsigned u = ((unsigned)(unsigned short)s) << 16;
    union { unsigned u; float f; } c; c.u = u; return c.f;
}
__device__ inline short f2bf(float f) {
    union { float f; unsigned u; } c; c.f = f;
    unsigned u = c.u;
    unsigned r = (u + 0x7fffu + ((u >> 16) & 1u)) >> 16;
    return (short)r;
}

__device__ __forceinline__ void gload_lds16(short* lds, const short* g) {
    __builtin_amdgcn_global_load_lds(
        (const __attribute__((address_space(1))) unsigned int*)g,
        (__attribute__((address_space(3))) unsigned int*)lds, 16, 0, 0);
}

// ---------------- weight convert f32 -> bf16 ----------------
__global__ void cvt_kernel(const float* __restrict__ src, short* __restrict__ dst, int n) {
    int i = blockIdx.x * blockDim.x + threadIdx.x;
    int stride = gridDim.x * blockDim.x;
    for (; i < n; i += stride) dst[i] = f2bf(src[i]);
}

// ---------------- Mt[g][e][d] = scale * sum_o Wq[g][o][d] * Wk[g][o][e] --------------
__global__ void prep_m_kernel(const float* __restrict__ wq, const float* __restrict__ wk,
                              short* __restrict__ mt) {
    int ge = blockIdx.x;            // g*128 + e
    int g = ge >> 7, e = ge & 127;
    int d = threadIdx.x;            // 128 threads
    const float* Wq = wq + (size_t)g * GD * GD;
    const float* Wk = wk + (size_t)g * GD * GD;
    float acc = 0.0f;
    for (int o = 0; o < GD; ++o)
        acc += Wq[(size_t)o * GD + d] * Wk[(size_t)o * GD + e];
    mt[(size_t)ge * GD + d] = f2bf(acc * 0.08838834764831845f);
}

// ---------------- Wov[o][g*128+i0] = sum_d Wo[o][g*128+d] * Wv[g][d][i0] -------------
__global__ void prep_wov_kernel(const float* __restrict__ wo, const float* __restrict__ wv,
                                short* __restrict__ wov) {
    int o = blockIdx.x;             // 512 blocks
    int i = threadIdx.x;            // 512 threads
    int g = i >> 7, i0 = i & 127;
    float acc = 0.0f;
    for (int d = 0; d < GD; ++d)
        acc += wo[(size_t)o * DIM + g * GD + d] * wv[((size_t)g * GD + d) * GD + i0];
    wov[(size_t)o * DIM + i] = f2bf(acc);
}

// ---------------- LayerNorm (f32 in -> bf16 out) ----------------
__global__ void ln_kernel(const float* __restrict__ in, const float* __restrict__ g,
                          const float* __restrict__ b, short* __restrict__ out) {
    int row = blockIdx.x;
    int tid = threadIdx.x; // 128 threads, 4 elems each
    if (row >= NPTS) {
        short4v z; z[0] = 0; z[1] = 0; z[2] = 0; z[3] = 0;
        *(short4v*)(out + (size_t)row * DIM + tid * 4) = z;
        return;
    }
    const float4 x = *(const float4*)(in + (size_t)row * DIM + tid * 4);
    float s  = x.x + x.y + x.z + x.w;
    float sq = x.x * x.x + x.y * x.y + x.z * x.z + x.w * x.w;
    for (int m = 1; m < 64; m <<= 1) {
        s  += __shfl_xor(s, m);
        sq += __shfl_xor(sq, m);
    }
    __shared__ float ss[2], ssq[2];
    int wv = tid >> 6;
    if ((tid & 63) == 0) { ss[wv] = s; ssq[wv] = sq; }
    __syncthreads();
    s = ss[0] + ss[1]; sq = ssq[0] + ssq[1];
    float mu = s * (1.0f / DIM);
    float var = sq * (1.0f / DIM) - mu * mu;
    float rstd = rsqrtf(var + EPS);
    const float4 gg = *(const float4*)(g + tid * 4);
    const float4 bb = *(const float4*)(b + tid * 4);
    short4v o;
    o[0] = f2bf((x.x - mu) * rstd * gg.x + bb.x);
    o[1] = f2bf((x.y - mu) * rstd * gg.y + bb.y);
    o[2] = f2bf((x.z - mu) * rstd * gg.z + bb.z);
    o[3] = f2bf((x.w - mu) * rstd * gg.w + bb.w);
    *(short4v*)(out + (size_t)row * DIM + tid * 4) = o;
}

// ---------------- LayerNorm (bf16 in -> bf16 out), for res2 ----------------
__global__ void ln_bf16_kernel(const short* __restrict__ in, const float* __restrict__ g,
                               const float* __restrict__ b, short* __restrict__ out) {
    int row = blockIdx.x;
    int tid = threadIdx.x; // 128 threads, 4 elems each
    if (row >= NPTS) {
        short4v z; z[0] = 0; z[1] = 0; z[2] = 0; z[3] = 0;
        *(short4v*)(out + (size_t)row * DIM + tid * 4) = z;
        return;
    }
    short4v xi = *(const short4v*)(in + (size_t)row * DIM + tid * 4);
    float x0 = bf2f(xi[0]), x1 = bf2f(xi[1]), x2 = bf2f(xi[2]), x3 = bf2f(xi[3]);
    float s  = x0 + x1 + x2 + x3;
    float sq = x0 * x0 + x1 * x1 + x2 * x2 + x3 * x3;
    for (int m = 1; m < 64; m <<= 1) {
        s  += __shfl_xor(s, m);
        sq += __shfl_xor(sq, m);
    }
    __shared__ float ss[2], ssq[2];
    int wv = tid >> 6;
    if ((tid & 63) == 0) { ss[wv] = s; ssq[wv] = sq; }
    __syncthreads();
    s = ss[0] + ss[1]; sq = ssq[0] + ssq[1];
    float mu = s * (1.0f / DIM);
    float var = sq * (1.0f / DIM) - mu * mu;
    float rstd = rsqrtf(var + EPS);
    const float4 gg = *(const float4*)(g + tid * 4);
    const float4 bb = *(const float4*)(b + tid * 4);
    short4v o;
    o[0] = f2bf((x0 - mu) * rstd * gg.x + bb.x);
    o[1] = f2bf((x1 - mu) * rstd * gg.y + bb.y);
    o[2] = f2bf((x2 - mu) * rstd * gg.z + bb.z);
    o[3] = f2bf((x3 - mu) * rstd * gg.w + bb.w);
    *(short4v*)(out + (size_t)row * DIM + tid * 4) = o;
}

// ---------------- 128x128 GEMM core (qproj only), BK=32, 2-phase dbuf ----------------
__device__ __forceinline__ void stage_tile(short* As, short* Bs,
        const short* aS, int as_, const short* bS, int bs_, int tid) {
    int ldRow = tid >> 2;            // 0..63
    int ldCol = (tid & 3) * 8;       // element col within BK=32
    gload_lds16(As + (ldRow)      * 32 + ldCol, aS + (size_t)(ldRow)      * as_ + ldCol);
    gload_lds16(As + (ldRow + 64) * 32 + ldCol, aS + (size_t)(ldRow + 64) * as_ + ldCol);
    gload_lds16(Bs + (ldRow)      * 32 + ldCol, bS + (size_t)(ldRow)      * bs_ + ldCol);
    gload_lds16(Bs + (ldRow + 64) * 32 + ldCol, bS + (size_t)(ldRow + 64) * bs_ + ldCol);
}

__device__ __forceinline__ void compute_tile(const short* As, const short* Bs,
        int wr, int wc, int r, int ks, f32x4 (&acc)[4][4]) {
    bf16x8 a[4];
    #pragma unroll
    for (int m = 0; m < 4; ++m)
        a[m] = *(const bf16x8*)(As + (wr * 64 + m * 16 + r) * 32 + ks * 8);
    #pragma unroll
    for (int n = 0; n < 4; ++n) {
        bf16x8 b = *(const bf16x8*)(Bs + (wc * 64 + n * 16 + r) * 32 + ks * 8);
        #pragma unroll
        for (int m = 0; m < 4; ++m)
            acc[m][n] = __builtin_amdgcn_mfma_f32_16x16x32_bf16(a[m], b, acc[m][n], 0, 0, 0);
    }
}

template<int NK>
__device__ __forceinline__ void gemm_tile(
        const short* __restrict__ aBase, int as_,
        const short* __restrict__ bBase, int bs_,
        short* As0, short* Bs0, short* As1, short* Bs1, f32x4 (&acc)[4][4]) {
    int tid = threadIdx.x;
    int lane = tid & 63, wave = tid >> 6;
    int wr = wave >> 1, wc = wave & 1;
    int r = lane & 15, ks = lane >> 4;
    stage_tile(As0, Bs0, aBase, as_, bBase, bs_, tid);
    __syncthreads();
    #pragma unroll
    for (int kt = 0; kt < NK; kt += 2) {
        if (kt + 1 < NK)
            stage_tile(As1, Bs1, aBase + (kt + 1) * 32, as_, bBase + (kt + 1) * 32, bs_, tid);
        compute_tile(As0, Bs0, wr, wc, r, ks, acc);
        __syncthreads();
        if (kt + 2 < NK)
            stage_tile(As0, Bs0, aBase + (kt + 2) * 32, as_, bBase + (kt + 2) * 32, bs_, tid);
        compute_tile(As1, Bs1, wr, wc, r, ks, acc);
        __syncthreads();
    }
}

// ====== 64x128 GEMM core (big GEMMs): 2-wave blocks, BK=32, 2-phase dbuf =============
// 24 KB LDS + ~132 unified VGPR -> 6 independent blocks/CU (vs 3 of the 4-wave core):
// doubles the count of independent staging streams; barrier width is 2 waves.
__device__ __forceinline__ void stage_tile2(short* As, short* Bs,
        const short* aS, int as_, const short* bS, int bs_, int tid) {
    int row = tid >> 2;              // 0..31
    int col = (tid & 3) * 8;         // element col within BK=32
    gload_lds16(As + (row)      * 32 + col, aS + (size_t)(row)      * as_ + col);
    gload_lds16(As + (row + 32) * 32 + col, aS + (size_t)(row + 32) * as_ + col);
    gload_lds16(Bs + (row)      * 32 + col, bS + (size_t)(row)      * bs_ + col);
    gload_lds16(Bs + (row + 32) * 32 + col, bS + (size_t)(row + 32) * bs_ + col);
    gload_lds16(Bs + (row + 64) * 32 + col, bS + (size_t)(row + 64) * bs_ + col);
    gload_lds16(Bs + (row + 96) * 32 + col, bS + (size_t)(row + 96) * bs_ + col);
}

__device__ __forceinline__ void compute_tile2(const short* As, const short* Bs,
        int wc, int r, int ks, f32x4 (&acc)[4][4]) {
    bf16x8 a[4];
    #pragma unroll
    for (int m = 0; m < 4; ++m)
        a[m] = *(const bf16x8*)(As + (m * 16 + r) * 32 + ks * 8);
    #pragma unroll
    for (int n = 0; n < 4; ++n) {
        bf16x8 b = *(const bf16x8*)(Bs + (wc * 64 + n * 16 + r) * 32 + ks * 8);
        #pragma unroll
        for (int m = 0; m < 4; ++m)
            acc[m][n] = __builtin_amdgcn_mfma_f32_16x16x32_bf16(a[m], b, acc[m][n], 0, 0, 0);
    }
}

template<int NK>
__device__ __forceinline__ void gemm_tile2(
        const short* __restrict__ aBase, int as_,
        const short* __restrict__ bBase, int bs_,
        short* As0, short* Bs0, short* As1, short* Bs1, f32x4 (&acc)[4][4]) {
    int tid = threadIdx.x;
    int lane = tid & 63, wc = tid >> 6;   // 2 waves: wc in {0,1}
    int r = lane & 15, ks = lane >> 4;
    stage_tile2(As0, Bs0, aBase, as_, bBase, bs_, tid);
    __syncthreads();
    #pragma unroll
    for (int kt = 0; kt < NK; kt += 2) {
        if (kt + 1 < NK)
            stage_tile2(As1, Bs1, aBase + (kt + 1) * 32, as_, bBase + (kt + 1) * 32, bs_, tid);
        compute_tile2(As0, Bs0, wc, r, ks, acc);
        __syncthreads();
        if (kt + 2 < NK)
            stage_tile2(As0, Bs0, aBase + (kt + 2) * 32, as_, bBase + (kt + 2) * 32, bs_, tid);
        compute_tile2(As1, Bs1, wc, r, ks, acc);
        __syncthreads();
    }
}

#define GEMM2_LDS \
    __shared__ short As0[64 * 32], Bs0[128 * 32], As1[64 * 32], Bs1[128 * 32]

// ---------------- q' projection (128^2 core) -----------------------------------------
__global__ __launch_bounds__(256) void qproj_kernel(
        const short* __restrict__ x, const short* __restrict__ mt,
        short* __restrict__ qp) {
    __shared__ short As0[128 * 32], Bs0[128 * 32], As1[128 * 32], Bs1[128 * 32];
    int nwg = gridDim.x;             // 782*4 = 3128, %8==0
    int bid = blockIdx.x;
    int tile = (bid & 7) * (nwg >> 3) + (bid >> 3);
    int rb = tile >> 2, g = tile & 3;
    int rowbase = rb * 128;
    int tid = threadIdx.x;
    int lane = tid & 63, wave = tid >> 6;
    int wr = wave >> 1, wc = wave & 1;
    int r = lane & 15, ks = lane >> 4;
    f32x4 acc[4][4];
    #pragma unroll
    for (int m = 0; m < 4; ++m)
        #pragma unroll
        for (int n = 0; n < 4; ++n)
            #pragma unroll
            for (int e = 0; e < 4; ++e) acc[m][n][e] = 0.0f;
    gemm_tile<4>(x + (size_t)rowbase * DIM + g * GD, DIM,
                 mt + (size_t)g * GD * GD, GD, As0, Bs0, As1, Bs1, acc);
    #pragma unroll
    for (int m = 0; m < 4; ++m)
        #pragma unroll
        for (int n = 0; n < 4; ++n)
            #pragma unroll
            for (int rr = 0; rr < 4; ++rr) {
                int orow = rowbase + wr * 64 + m * 16 + ks * 4 + rr;
                int lcol = wc * 64 + n * 16 + r;
                qp[(size_t)orow * DIM + g * GD + lcol] = f2bf(acc[m][n][rr]);
            }
}

// ---------------- attention ----------------------------------------------------------
__global__ __launch_bounds__(256) void attn_kernel(
        const short* __restrict__ qp, const short* __restrict__ x,
        const int* __restrict__ nbrs, short* __restrict__ t_out) {
    int b = blockIdx.x;
    int xcd = b & 7;
    int g = xcd >> 1;
    int quad = (b >> 3) * 2 + (xcd & 1);   // 0..24999
    int tid = threadIdx.x;
    int wv = tid >> 6, lane = tid & 63;
    int n = quad * 4 + wv;                 // 0..99999
    int s = lane >> 4, t = lane & 15;
    int4 nbj = *(const int4*)(nbrs + (size_t)n * K_NBR + s * 4);
    int nbarr[4] = {nbj.x, nbj.y, nbj.z, nbj.w};
    size_t goff = (size_t)g * GD + t * 8;
    size_t qbase = (size_t)n * DIM + goff;
    bf16x8 qf = *(const bf16x8*)(qp + qbase);
    float qv[8];
    #pragma unroll
    for (int e = 0; e < 8; ++e) qv[e] = bf2f(qf[e]);
    bf16x8 xf[4];
    #pragma unroll
    for (int p = 0; p < 4; ++p)
        xf[p] = *(const bf16x8*)(x + (size_t)nbarr[p] * DIM + goff);
    float sc[4];
    #pragma unroll
    for (int p = 0; p < 4; ++p) {
        float dd = 0.0f;
        #pragma unroll
        for (int e = 0; e < 8; ++e) dd += qv[e] * bf2f(xf[p][e]);
        dd += __shfl_xor(dd, 1);
        dd += __shfl_xor(dd, 2);
        dd += __shfl_xor(dd, 4);
        dd += __shfl_xor(dd, 8);
        sc[p] = dd;
    }
    float mx = fmaxf(fmaxf(sc[0], sc[1]), fmaxf(sc[2], sc[3]));
    mx = fmaxf(mx, __shfl_xor(mx, 16));
    mx = fmaxf(mx, __shfl_xor(mx, 32));
    float ew[4]; float ssum = 0.0f;
    #pragma unroll
    for (int p = 0; p < 4; ++p) { ew[p] = __expf(sc[p] - mx); ssum += ew[p]; }
    ssum += __shfl_xor(ssum, 16);
    ssum += __shfl_xor(ssum, 32);
    float acc[8];
    #pragma unroll
    for (int d0 = 0; d0 < 8; ++d0) acc[d0] = 0.0f;
    #pragma unroll
    for (int p = 0; p < 4; ++p) {
        #pragma unroll
        for (int d0 = 0; d0 < 8; ++d0) acc[d0] += ew[p] * bf2f(xf[p][d0]);
    }
    #pragma unroll
    for (int d0 = 0; d0 < 8; ++d0) {
        acc[d0] += __shfl_xor(acc[d0], 16);
        acc[d0] += __shfl_xor(acc[d0], 32);
    }
    if (s == 0) {
        float inv = 1.0f / ssum;
        bf16x8 o;
        #pragma unroll
        for (int d0 = 0; d0 < 8; ++d0) o[d0] = f2bf(acc[d0] * inv);
        *(bf16x8*)(t_out + qbase) = o;
    }
}

// ------- res2 = t @ Wov.T + bo + features (residual), stored BF16 (64x128 core) ------
__global__ __launch_bounds__(128) void outproj_kernel(
        const short* __restrict__ tbuf, const short* __restrict__ wov,
        const float* __restrict__ bo, const float* __restrict__ features,
        short* __restrict__ res2) {
    GEMM2_LDS;
    int nwg = gridDim.x;             // 1564*4 = 6256
    int bid = blockIdx.x;
    int tile = (bid & 7) * (nwg >> 3) + (bid >> 3);
    int rb = tile >> 2, cb = tile & 3;
    int rowbase = rb * 64, colbase = cb * 128;
    int tid = threadIdx.x;
    int lane = tid & 63, wc = tid >> 6;
    int r = lane & 15, ks = lane >> 4;
    f32x4 acc[4][4];
    #pragma unroll
    for (int m = 0; m < 4; ++m)
        #pragma unroll
        for (int n = 0; n < 4; ++n)
            #pragma unroll
            for (int e = 0; e < 4; ++e) acc[m][n][e] = 0.0f;
    gemm_tile2<16>(tbuf + (size_t)rowbase * DIM, DIM,
                   wov + (size_t)colbase * DIM, DIM, As0, Bs0, As1, Bs1, acc);
    #pragma unroll
    for (int m = 0; m < 4; ++m)
        #pragma unroll
        for (int n = 0; n < 4; ++n)
            #pragma unroll
            for (int rr = 0; rr < 4; ++rr) {
                int orow = rowbase + m * 16 + ks * 4 + rr;
                int ocol = colbase + wc * 64 + n * 16 + r;
                if (orow < NPTS) {
                    float val = acc[m][n][rr] + bo[ocol] + features[(size_t)orow * DIM + ocol];
                    res2[(size_t)orow * DIM + ocol] = f2bf(val);
                }
            }
}

// ---------------- FFN1: h = gelu(y @ W1.T + b1), bf16 out (64x128 core) --------------
__global__ __launch_bounds__(128) void ffn1_kernel(
        const short* __restrict__ y, const short* __restrict__ w1,
        const float* __restrict__ b1, short* __restrict__ h) {
    GEMM2_LDS;
    int nwg = gridDim.x;             // 1564*8 = 12512
    int bid = blockIdx.x;
    int tile = (bid & 7) * (nwg >> 3) + (bid >> 3);
    int rb = tile >> 3, cb = tile & 7;
    int rowbase = rb * 64, colbase = cb * 128;
    int tid = threadIdx.x;
    int lane = tid & 63, wc = tid >> 6;
    int r = lane & 15, ks = lane >> 4;
    f32x4 acc[4][4];
    #pragma unroll
    for (int m = 0; m < 4; ++m)
        #pragma unroll
        for (int n = 0; n < 4; ++n)
            #pragma unroll
            for (int e = 0; e < 4; ++e) acc[m][n][e] = 0.0f;
    gemm_tile2<16>(y + (size_t)rowbase * DIM, DIM,
                   w1 + (size_t)colbase * DIM, DIM, As0, Bs0, As1, Bs1, acc);
    #pragma unroll
    for (int m = 0; m < 4; ++m)
        #pragma unroll
        for (int n = 0; n < 4; ++n)
            #pragma unroll
            for (int rr = 0; rr < 4; ++rr) {
                int orow = rowbase + m * 16 + ks * 4 + rr;
                int ocol = colbase + wc * 64 + n * 16 + r;
                float xv = acc[m][n][rr] + b1[ocol];
                // exact-GELU via clamped tanh form (max abs err ~3e-3)
                float xc = fminf(fmaxf(xv, -9.0f), 9.0f);
                float u = xc * (0.7978845608028654f + 0.0356774081f * xc * xc);
                float e2 = __expf(2.0f * u);
                float th = (e2 - 1.0f) / (e2 + 1.0f);
                float gl = 0.5f * xv * (1.0f + th);
                h[(size_t)orow * (2 * DIM) + ocol] = f2bf(gl);
            }
}

// ------- FFN2: d_out = h @ W2.T + b2 + res2(bf16) (64x128 core) ----------------------
__global__ __launch_bounds__(128) void ffn2_kernel(
        const short* __restrict__ h, const short* __restrict__ w2,
        const float* __restrict__ b2, const short* __restrict__ res2,
        float* __restrict__ out) {
    GEMM2_LDS;
    int nwg = gridDim.x;             // 1564*4 = 6256
    int bid = blockIdx.x;
    int tile = (bid & 7) * (nwg >> 3) + (bid >> 3);
    int rb = tile >> 2, cb = tile & 3;
    int rowbase = rb * 64, colbase = cb * 128;
    int tid = threadIdx.x;
    int lane = tid & 63, wc = tid >> 6;
    int r = lane & 15, ks = lane >> 4;
    f32x4 acc[4][4];
    #pragma unroll
    for (int m = 0; m < 4; ++m)
        #pragma unroll
        for (int n = 0; n < 4; ++n)
            #pragma unroll
            for (int e = 0; e < 4; ++e) acc[m][n][e] = 0.0f;
    gemm_tile2<32>(h + (size_t)rowbase * (2 * DIM), 2 * DIM,
                   w2 + (size_t)colbase * (2 * DIM), 2 * DIM, As0, Bs0, As1, Bs1, acc);
    #pragma unroll
    for (int m = 0; m < 4; ++m)
        #pragma unroll
        for (int n = 0; n < 4; ++n)
            #pragma unroll
            for (int rr = 0; rr < 4; ++rr) {
                int orow = rowbase + m * 16 + ks * 4 + rr;
                int ocol = colbase + wc * 64 + n * 16 + r;
                if (orow < NPTS) {
                    size_t idx = (size_t)orow * DIM + ocol;
                    out[idx] = acc[m][n][rr] + b2[ocol] + bf2f(res2[idx]);
                }
            }
}

extern "C" void kernel_launch(void* const* d_in, const int* in_sizes, int n_in,
                              void* d_out, int out_size, void* d_ws, size_t ws_size,
                              hipStream_t stream) {
    const float* features = (const float*)d_in[0];
    const int*   neighbors = (const int*)d_in[2];
    const float* Wq = (const float*)d_in[3];
    const float* Wk = (const float*)d_in[4];
    const float* Wv = (const float*)d_in[5];
    const float* Wo = (const float*)d_in[6];
    const float* bo = (const float*)d_in[7];
    const float* ln1_g = (const float*)d_in[8];
    const float* ln1_b = (const float*)d_in[9];
    const float* ln2_g = (const float*)d_in[10];
    const float* ln2_b = (const float*)d_in[11];
    const float* W1 = (const float*)d_in[12];
    const float* b1 = (const float*)d_in[13];
    const float* W2 = (const float*)d_in[14];
    const float* b2 = (const float*)d_in[15];
    float* out = (float*)d_out;

    size_t slotElems = (size_t)PAD_ROWS * DIM;
    short* s0 = (short*)d_ws;            // x (ln1) -> y (ln2)
    short* s1 = s0 + slotElems;          // q' -> h (low half; s1+s2 contiguous = h[PAD][1024])
    short* s2 = s1 + slotElems;          // t  -> h (high half)
    short* s3 = s2 + slotElems;          // res2 (bf16)
    short* mt_b  = s3 + slotElems;       // 4*128*128
    short* wov_b = mt_b + GRP * GD * GD; // 512*512
    short* w1_b  = wov_b + DIM * DIM;    // 1024*512
    short* w2_b  = w1_b + 2 * DIM * DIM; // 512*1024

    cvt_kernel<<<256, 256, 0, stream>>>(W1, w1_b, 2 * DIM * DIM);
    cvt_kernel<<<256, 256, 0, stream>>>(W2, w2_b, 2 * DIM * DIM);
    prep_m_kernel<<<GRP * GD, GD, 0, stream>>>(Wq, Wk, mt_b);
    prep_wov_kernel<<<DIM, DIM, 0, stream>>>(Wo, Wv, wov_b);

    // LN1: features -> x (bf16), zero-padded rows
    ln_kernel<<<PAD_ROWS, 128, 0, stream>>>(features, ln1_g, ln1_b, s0);

    // q' = Mt x
    qproj_kernel<<<(PAD_ROWS / 128) * 4, 256, 0, stream>>>(s0, mt_b, s1);

    // attention: gather x only -> t in s2
    attn_kernel<<<NPTS, 256, 0, stream>>>(s1, s0, neighbors, s2);

    // res2 = t @ Wov.T + bo + features  (bf16, in s3)
    outproj_kernel<<<(PAD_ROWS / 64) * 4, 128, 0, stream>>>(s2, wov_b, bo, features, s3);

    // LN2: res2 (bf16) -> y (bf16) in s0
    ln_bf16_kernel<<<PAD_ROWS, 128, 0, stream>>>(s3, ln2_g, ln2_b, s0);

    // FFN1: h = gelu(y @ W1.T + b1) -> s1..s2 region (PAD x 1024 bf16)
    ffn1_kernel<<<(PAD_ROWS / 64) * 8, 128, 0, stream>>>(s0, w1_b, b1, s1);

    // FFN2: d_out = h @ W2.T + b2 + res2
    ffn2_kernel<<<(PAD_ROWS / 64) * 4, 128, 0, stream>>>(s1, w2_b, b2, s3, out);
}

// Round 17
// 1074.651 us; speedup vs baseline: 1.0942x; 1.0942x over previous
//
#include <hip/hip_runtime.h>
#include <hip/hip_bf16.h>
#include <math.h>

#define NPTS 100000
#define PAD_ROWS 100096   // 782 * 128
#define DIM 512
#define GRP 4
#define GD 128
#define K_NBR 16
#define EPS 1e-5f

using bf16x8 = __attribute__((ext_vector_type(8))) short;
using f32x4  = __attribute__((ext_vector_type(4))) float;
using short4v = __attribute__((ext_vector_type(4))) short;

__device__ inline float bf2f(short s) {
    unsigned u = ((unsigned)(unsigned short)s) << 16;
    union { unsigned u; float f; } c; c.u = u; return c.f;
}
__device__ inline short f2bf(float f) {
    union { float f; unsigned u; } c; c.f = f;
    unsigned u = c.u;
    unsigned r = (u + 0x7fffu + ((u >> 16) & 1u)) >> 16;
    return (short)r;
}

__device__ __forceinline__ void gload_lds16(short* lds, const short* g) {
    __builtin_amdgcn_global_load_lds(
        (const __attribute__((address_space(1))) unsigned int*)g,
        (__attribute__((address_space(3))) unsigned int*)lds, 16, 0, 0);
}

// ---------------- weight convert f32 -> bf16 ----------------
__global__ void cvt_kernel(const float* __restrict__ src, short* __restrict__ dst, int n) {
    int i = blockIdx.x * blockDim.x + threadIdx.x;
    int stride = gridDim.x * blockDim.x;
    for (; i < n; i += stride) dst[i] = f2bf(src[i]);
}

// ---------------- Mt[g][e][d] = scale * sum_o Wq[g][o][d] * Wk[g][o][e] --------------
__global__ void prep_m_kernel(const float* __restrict__ wq, const float* __restrict__ wk,
                              short* __restrict__ mt) {
    int ge = blockIdx.x;            // g*128 + e
    int g = ge >> 7, e = ge & 127;
    int d = threadIdx.x;            // 128 threads
    const float* Wq = wq + (size_t)g * GD * GD;
    const float* Wk = wk + (size_t)g * GD * GD;
    float acc = 0.0f;
    for (int o = 0; o < GD; ++o)
        acc += Wq[(size_t)o * GD + d] * Wk[(size_t)o * GD + e];
    mt[(size_t)ge * GD + d] = f2bf(acc * 0.08838834764831845f);
}

// ---------------- Wov[o][g*128+i0] = sum_d Wo[o][g*128+d] * Wv[g][d][i0] -------------
__global__ void prep_wov_kernel(const float* __restrict__ wo, const float* __restrict__ wv,
                                short* __restrict__ wov) {
    int o = blockIdx.x;             // 512 blocks
    int i = threadIdx.x;            // 512 threads
    int g = i >> 7, i0 = i & 127;
    float acc = 0.0f;
    for (int d = 0; d < GD; ++d)
        acc += wo[(size_t)o * DIM + g * GD + d] * wv[((size_t)g * GD + d) * GD + i0];
    wov[(size_t)o * DIM + i] = f2bf(acc);
}

// ---------------- LayerNorm (f32 in -> bf16 out) ----------------
__global__ void ln_kernel(const float* __restrict__ in, const float* __restrict__ g,
                          const float* __restrict__ b, short* __restrict__ out) {
    int row = blockIdx.x;
    int tid = threadIdx.x; // 128 threads, 4 elems each
    if (row >= NPTS) {
        short4v z; z[0] = 0; z[1] = 0; z[2] = 0; z[3] = 0;
        *(short4v*)(out + (size_t)row * DIM + tid * 4) = z;
        return;
    }
    const float4 x = *(const float4*)(in + (size_t)row * DIM + tid * 4);
    float s  = x.x + x.y + x.z + x.w;
    float sq = x.x * x.x + x.y * x.y + x.z * x.z + x.w * x.w;
    for (int m = 1; m < 64; m <<= 1) {
        s  += __shfl_xor(s, m);
        sq += __shfl_xor(sq, m);
    }
    __shared__ float ss[2], ssq[2];
    int wv = tid >> 6;
    if ((tid & 63) == 0) { ss[wv] = s; ssq[wv] = sq; }
    __syncthreads();
    s = ss[0] + ss[1]; sq = ssq[0] + ssq[1];
    float mu = s * (1.0f / DIM);
    float var = sq * (1.0f / DIM) - mu * mu;
    float rstd = rsqrtf(var + EPS);
    const float4 gg = *(const float4*)(g + tid * 4);
    const float4 bb = *(const float4*)(b + tid * 4);
    short4v o;
    o[0] = f2bf((x.x - mu) * rstd * gg.x + bb.x);
    o[1] = f2bf((x.y - mu) * rstd * gg.y + bb.y);
    o[2] = f2bf((x.z - mu) * rstd * gg.z + bb.z);
    o[3] = f2bf((x.w - mu) * rstd * gg.w + bb.w);
    *(short4v*)(out + (size_t)row * DIM + tid * 4) = o;
}

// ---------------- LayerNorm (bf16 in -> bf16 out), for res2 ----------------
__global__ void ln_bf16_kernel(const short* __restrict__ in, const float* __restrict__ g,
                               const float* __restrict__ b, short* __restrict__ out) {
    int row = blockIdx.x;
    int tid = threadIdx.x; // 128 threads, 4 elems each
    if (row >= NPTS) {
        short4v z; z[0] = 0; z[1] = 0; z[2] = 0; z[3] = 0;
        *(short4v*)(out + (size_t)row * DIM + tid * 4) = z;
        return;
    }
    short4v xi = *(const short4v*)(in + (size_t)row * DIM + tid * 4);
    float x0 = bf2f(xi[0]), x1 = bf2f(xi[1]), x2 = bf2f(xi[2]), x3 = bf2f(xi[3]);
    float s  = x0 + x1 + x2 + x3;
    float sq = x0 * x0 + x1 * x1 + x2 * x2 + x3 * x3;
    for (int m = 1; m < 64; m <<= 1) {
        s  += __shfl_xor(s, m);
        sq += __shfl_xor(sq, m);
    }
    __shared__ float ss[2], ssq[2];
    int wv = tid >> 6;
    if ((tid & 63) == 0) { ss[wv] = s; ssq[wv] = sq; }
    __syncthreads();
    s = ss[0] + ss[1]; sq = ssq[0] + ssq[1];
    float mu = s * (1.0f / DIM);
    float var = sq * (1.0f / DIM) - mu * mu;
    float rstd = rsqrtf(var + EPS);
    const float4 gg = *(const float4*)(g + tid * 4);
    const float4 bb = *(const float4*)(b + tid * 4);
    short4v o;
    o[0] = f2bf((x0 - mu) * rstd * gg.x + bb.x);
    o[1] = f2bf((x1 - mu) * rstd * gg.y + bb.y);
    o[2] = f2bf((x2 - mu) * rstd * gg.z + bb.z);
    o[3] = f2bf((x3 - mu) * rstd * gg.w + bb.w);
    *(short4v*)(out + (size_t)row * DIM + tid * 4) = o;
}

// ---------------- 128x128 GEMM primitives, BK=32 -------------------------------------
__device__ __forceinline__ void stage_tile(short* As, short* Bs,
        const short* aS, int as_, const short* bS, int bs_, int tid) {
    int ldRow = tid >> 2;            // 0..63
    int ldCol = (tid & 3) * 8;       // element col within BK=32
    gload_lds16(As + (ldRow)      * 32 + ldCol, aS + (size_t)(ldRow)      * as_ + ldCol);
    gload_lds16(As + (ldRow + 64) * 32 + ldCol, aS + (size_t)(ldRow + 64) * as_ + ldCol);
    gload_lds16(Bs + (ldRow)      * 32 + ldCol, bS + (size_t)(ldRow)      * bs_ + ldCol);
    gload_lds16(Bs + (ldRow + 64) * 32 + ldCol, bS + (size_t)(ldRow + 64) * bs_ + ldCol);
}

__device__ __forceinline__ void compute_tile(const short* As, const short* Bs,
        int wr, int wc, int r, int ks, f32x4 (&acc)[4][4]) {
    bf16x8 a[4];
    #pragma unroll
    for (int m = 0; m < 4; ++m)
        a[m] = *(const bf16x8*)(As + (wr * 64 + m * 16 + r) * 32 + ks * 8);
    #pragma unroll
    for (int n = 0; n < 4; ++n) {
        bf16x8 b = *(const bf16x8*)(Bs + (wc * 64 + n * 16 + r) * 32 + ks * 8);
        #pragma unroll
        for (int m = 0; m < 4; ++m)
            acc[m][n] = __builtin_amdgcn_mfma_f32_16x16x32_bf16(a[m], b, acc[m][n], 0, 0, 0);
    }
}

// ---- r11 2-phase core (qproj, K=128 only) ----
template<int NK>
__device__ __forceinline__ void gemm_tile(
        const short* __restrict__ aBase, int as_,
        const short* __restrict__ bBase, int bs_,
        short* As0, short* Bs0, short* As1, short* Bs1, f32x4 (&acc)[4][4]) {
    int tid = threadIdx.x;
    int lane = tid & 63, wave = tid >> 6;
    int wr = wave >> 1, wc = wave & 1;
    int r = lane & 15, ks = lane >> 4;
    stage_tile(As0, Bs0, aBase, as_, bBase, bs_, tid);
    __syncthreads();
    #pragma unroll
    for (int kt = 0; kt < NK; kt += 2) {
        if (kt + 1 < NK)
            stage_tile(As1, Bs1, aBase + (kt + 1) * 32, as_, bBase + (kt + 1) * 32, bs_, tid);
        compute_tile(As0, Bs0, wr, wc, r, ks, acc);
        __syncthreads();
        if (kt + 2 < NK)
            stage_tile(As0, Bs0, aBase + (kt + 2) * 32, as_, bBase + (kt + 2) * 32, bs_, tid);
        compute_tile(As1, Bs1, wr, wc, r, ks, acc);
        __syncthreads();
    }
}

// ---- NEW: 3-deep counted-vmcnt pipeline (outproj/ffn1/ffn2) -------------------------
// 3 LDS buffers x 16 KB = 48 KB -> 3 blocks/CU retained. Per iter:
//   stage(t+2) -> vmcnt(8) [tiles t+1,t+2 stay in flight] -> barrier ->
//   compute(t) -> barrier.  Loads never drain to 0 in the main loop.
// Race audit: buf (t+2)%3 == buf (t-1)%3, last read by compute(t-1) which ALL waves
// completed at the preceding barrier. Data-ready: each wave passes its own vmcnt(8)
// before the pre-compute barrier => all waves' tile-t loads landed.
#define PB3 (128 * 32)                 // 4096 shorts A, 4096 shorts B per buffer
template<int NT>
__device__ __forceinline__ void gemmP3(
        const short* __restrict__ aBase, int as_,
        const short* __restrict__ bBase, int bs_,
        short* P, f32x4 (&acc)[4][4]) {
    int tid = threadIdx.x;
    int lane = tid & 63, wave = tid >> 6;
    int wr = wave >> 1, wc = wave & 1;
    int r = lane & 15, ks = lane >> 4;
    stage_tile(P,           P + PB3,           aBase,      as_, bBase,      bs_, tid);
    stage_tile(P + 2 * PB3, P + 3 * PB3,       aBase + 32, as_, bBase + 32, bs_, tid);
    #pragma unroll
    for (int t = 0; t < NT; ++t) {
        int bn = (t + 2) % 3, bc = t % 3;
        if (t + 2 < NT) {
            stage_tile(P + bn * 2 * PB3, P + bn * 2 * PB3 + PB3,
                       aBase + (size_t)(t + 2) * 32, as_,
                       bBase + (size_t)(t + 2) * 32, bs_, tid);
            asm volatile("s_waitcnt vmcnt(8)" ::: "memory");
        } else if (t + 1 < NT) {
            asm volatile("s_waitcnt vmcnt(4)" ::: "memory");
        } else {
            asm volatile("s_waitcnt vmcnt(0)" ::: "memory");
        }
        __builtin_amdgcn_s_barrier();
        __builtin_amdgcn_sched_barrier(0);
        compute_tile(P + bc * 2 * PB3, P + bc * 2 * PB3 + PB3, wr, wc, r, ks, acc);
        __builtin_amdgcn_s_barrier();
    }
}

#define GEMMP3_LDS __shared__ short P[6 * PB3]   // 48 KB

// ---------------- q' projection (r11 core) -------------------------------------------
__global__ __launch_bounds__(256) void qproj_kernel(
        const short* __restrict__ x, const short* __restrict__ mt,
        short* __restrict__ qp) {
    __shared__ short As0[128 * 32], Bs0[128 * 32], As1[128 * 32], Bs1[128 * 32];
    int nwg = gridDim.x;             // 782*4 = 3128, %8==0
    int bid = blockIdx.x;
    int tile = (bid & 7) * (nwg >> 3) + (bid >> 3);
    int rb = tile >> 2, g = tile & 3;
    int rowbase = rb * 128;
    int tid = threadIdx.x;
    int lane = tid & 63, wave = tid >> 6;
    int wr = wave >> 1, wc = wave & 1;
    int r = lane & 15, ks = lane >> 4;
    f32x4 acc[4][4];
    #pragma unroll
    for (int m = 0; m < 4; ++m)
        #pragma unroll
        for (int n = 0; n < 4; ++n)
            #pragma unroll
            for (int e = 0; e < 4; ++e) acc[m][n][e] = 0.0f;
    gemm_tile<4>(x + (size_t)rowbase * DIM + g * GD, DIM,
                 mt + (size_t)g * GD * GD, GD, As0, Bs0, As1, Bs1, acc);
    #pragma unroll
    for (int m = 0; m < 4; ++m)
        #pragma unroll
        for (int n = 0; n < 4; ++n)
            #pragma unroll
            for (int rr = 0; rr < 4; ++rr) {
                int orow = rowbase + wr * 64 + m * 16 + ks * 4 + rr;
                int lcol = wc * 64 + n * 16 + r;
                qp[(size_t)orow * DIM + g * GD + lcol] = f2bf(acc[m][n][rr]);
            }
}

// ---------------- attention ----------------------------------------------------------
__global__ __launch_bounds__(256) void attn_kernel(
        const short* __restrict__ qp, const short* __restrict__ x,
        const int* __restrict__ nbrs, short* __restrict__ t_out) {
    int b = blockIdx.x;
    int xcd = b & 7;
    int g = xcd >> 1;
    int quad = (b >> 3) * 2 + (xcd & 1);   // 0..24999
    int tid = threadIdx.x;
    int wv = tid >> 6, lane = tid & 63;
    int n = quad * 4 + wv;                 // 0..99999
    int s = lane >> 4, t = lane & 15;
    int4 nbj = *(const int4*)(nbrs + (size_t)n * K_NBR + s * 4);
    int nbarr[4] = {nbj.x, nbj.y, nbj.z, nbj.w};
    size_t goff = (size_t)g * GD + t * 8;
    size_t qbase = (size_t)n * DIM + goff;
    bf16x8 qf = *(const bf16x8*)(qp + qbase);
    float qv[8];
    #pragma unroll
    for (int e = 0; e < 8; ++e) qv[e] = bf2f(qf[e]);
    bf16x8 xf[4];
    #pragma unroll
    for (int p = 0; p < 4; ++p)
        xf[p] = *(const bf16x8*)(x + (size_t)nbarr[p] * DIM + goff);
    float sc[4];
    #pragma unroll
    for (int p = 0; p < 4; ++p) {
        float dd = 0.0f;
        #pragma unroll
        for (int e = 0; e < 8; ++e) dd += qv[e] * bf2f(xf[p][e]);
        dd += __shfl_xor(dd, 1);
        dd += __shfl_xor(dd, 2);
        dd += __shfl_xor(dd, 4);
        dd += __shfl_xor(dd, 8);
        sc[p] = dd;
    }
    float mx = fmaxf(fmaxf(sc[0], sc[1]), fmaxf(sc[2], sc[3]));
    mx = fmaxf(mx, __shfl_xor(mx, 16));
    mx = fmaxf(mx, __shfl_xor(mx, 32));
    float ew[4]; float ssum = 0.0f;
    #pragma unroll
    for (int p = 0; p < 4; ++p) { ew[p] = __expf(sc[p] - mx); ssum += ew[p]; }
    ssum += __shfl_xor(ssum, 16);
    ssum += __shfl_xor(ssum, 32);
    float acc[8];
    #pragma unroll
    for (int d0 = 0; d0 < 8; ++d0) acc[d0] = 0.0f;
    #pragma unroll
    for (int p = 0; p < 4; ++p) {
        #pragma unroll
        for (int d0 = 0; d0 < 8; ++d0) acc[d0] += ew[p] * bf2f(xf[p][d0]);
    }
    #pragma unroll
    for (int d0 = 0; d0 < 8; ++d0) {
        acc[d0] += __shfl_xor(acc[d0], 16);
        acc[d0] += __shfl_xor(acc[d0], 32);
    }
    if (s == 0) {
        float inv = 1.0f / ssum;
        bf16x8 o;
        #pragma unroll
        for (int d0 = 0; d0 < 8; ++d0) o[d0] = f2bf(acc[d0] * inv);
        *(bf16x8*)(t_out + qbase) = o;
    }
}

// ------- res2 = t @ Wov.T + bo + features (residual), stored BF16 (pipelined) --------
__global__ __launch_bounds__(256) void outproj_kernel(
        const short* __restrict__ tbuf, const short* __restrict__ wov,
        const float* __restrict__ bo, const float* __restrict__ features,
        short* __restrict__ res2) {
    GEMMP3_LDS;
    int nwg = gridDim.x;             // 782*4
    int bid = blockIdx.x;
    int tile = (bid & 7) * (nwg >> 3) + (bid >> 3);
    int rb = tile >> 2, cb = tile & 3;
    int rowbase = rb * 128, colbase = cb * 128;
    int tid = threadIdx.x;
    int lane = tid & 63, wave = tid >> 6;
    int wr = wave >> 1, wc = wave & 1;
    int r = lane & 15, ks = lane >> 4;
    f32x4 acc[4][4];
    #pragma unroll
    for (int m = 0; m < 4; ++m)
        #pragma unroll
        for (int n = 0; n < 4; ++n)
            #pragma unroll
            for (int e = 0; e < 4; ++e) acc[m][n][e] = 0.0f;
    gemmP3<16>(tbuf + (size_t)rowbase * DIM, DIM,
               wov + (size_t)colbase * DIM, DIM, P, acc);
    #pragma unroll
    for (int m = 0; m < 4; ++m)
        #pragma unroll
        for (int n = 0; n < 4; ++n)
            #pragma unroll
            for (int rr = 0; rr < 4; ++rr) {
                int orow = rowbase + wr * 64 + m * 16 + ks * 4 + rr;
                int ocol = colbase + wc * 64 + n * 16 + r;
                if (orow < NPTS) {
                    float val = acc[m][n][rr] + bo[ocol] + features[(size_t)orow * DIM + ocol];
                    res2[(size_t)orow * DIM + ocol] = f2bf(val);
                }
            }
}

// ---------------- FFN1: h = gelu(y @ W1.T + b1), bf16 out (pipelined) ----------------
__global__ __launch_bounds__(256) void ffn1_kernel(
        const short* __restrict__ y, const short* __restrict__ w1,
        const float* __restrict__ b1, short* __restrict__ h) {
    GEMMP3_LDS;
    int nwg = gridDim.x;             // 782*8
    int bid = blockIdx.x;
    int tile = (bid & 7) * (nwg >> 3) + (bid >> 3);
    int rb = tile >> 3, cb = tile & 7;
    int rowbase = rb * 128, colbase = cb * 128;
    int tid = threadIdx.x;
    int lane = tid & 63, wave = tid >> 6;
    int wr = wave >> 1, wc = wave & 1;
    int r = lane & 15, ks = lane >> 4;
    f32x4 acc[4][4];
    #pragma unroll
    for (int m = 0; m < 4; ++m)
        #pragma unroll
        for (int n = 0; n < 4; ++n)
            #pragma unroll
            for (int e = 0; e < 4; ++e) acc[m][n][e] = 0.0f;
    gemmP3<16>(y + (size_t)rowbase * DIM, DIM,
               w1 + (size_t)colbase * DIM, DIM, P, acc);
    #pragma unroll
    for (int m = 0; m < 4; ++m)
        #pragma unroll
        for (int n = 0; n < 4; ++n)
            #pragma unroll
            for (int rr = 0; rr < 4; ++rr) {
                int orow = rowbase + wr * 64 + m * 16 + ks * 4 + rr;
                int ocol = colbase + wc * 64 + n * 16 + r;
                float xv = acc[m][n][rr] + b1[ocol];
                // exact-GELU via clamped tanh form (max abs err ~3e-3)
                float xc = fminf(fmaxf(xv, -9.0f), 9.0f);
                float u = xc * (0.7978845608028654f + 0.0356774081f * xc * xc);
                float e2 = __expf(2.0f * u);
                float th = (e2 - 1.0f) / (e2 + 1.0f);
                float gl = 0.5f * xv * (1.0f + th);
                h[(size_t)orow * (2 * DIM) + ocol] = f2bf(gl);
            }
}

// ------- FFN2: d_out = h @ W2.T + b2 + res2(bf16) (pipelined) ------------------------
__global__ __launch_bounds__(256) void ffn2_kernel(
        const short* __restrict__ h, const short* __restrict__ w2,
        const float* __restrict__ b2, const short* __restrict__ res2,
        float* __restrict__ out) {
    GEMMP3_LDS;
    int nwg = gridDim.x;             // 782*4
    int bid = blockIdx.x;
    int tile = (bid & 7) * (nwg >> 3) + (bid >> 3);
    int rb = tile >> 2, cb = tile & 3;
    int rowbase = rb * 128, colbase = cb * 128;
    int tid = threadIdx.x;
    int lane = tid & 63, wave = tid >> 6;
    int wr = wave >> 1, wc = wave & 1;
    int r = lane & 15, ks = lane >> 4;
    f32x4 acc[4][4];
    #pragma unroll
    for (int m = 0; m < 4; ++m)
        #pragma unroll
        for (int n = 0; n < 4; ++n)
            #pragma unroll
            for (int e = 0; e < 4; ++e) acc[m][n][e] = 0.0f;
    gemmP3<32>(h + (size_t)rowbase * (2 * DIM), 2 * DIM,
               w2 + (size_t)colbase * (2 * DIM), 2 * DIM, P, acc);
    #pragma unroll
    for (int m = 0; m < 4; ++m)
        #pragma unroll
        for (int n = 0; n < 4; ++n)
            #pragma unroll
            for (int rr = 0; rr < 4; ++rr) {
                int orow = rowbase + wr * 64 + m * 16 + ks * 4 + rr;
                int ocol = colbase + wc * 64 + n * 16 + r;
                if (orow < NPTS) {
                    size_t idx = (size_t)orow * DIM + ocol;
                    out[idx] = acc[m][n][rr] + b2[ocol] + bf2f(res2[idx]);
                }
            }
}

extern "C" void kernel_launch(void* const* d_in, const int* in_sizes, int n_in,
                              void* d_out, int out_size, void* d_ws, size_t ws_size,
                              hipStream_t stream) {
    const float* features = (const float*)d_in[0];
    const int*   neighbors = (const int*)d_in[2];
    const float* Wq = (const float*)d_in[3];
    const float* Wk = (const float*)d_in[4];
    const float* Wv = (const float*)d_in[5];
    const float* Wo = (const float*)d_in[6];
    const float* bo = (const float*)d_in[7];
    const float* ln1_g = (const float*)d_in[8];
    const float* ln1_b = (const float*)d_in[9];
    const float* ln2_g = (const float*)d_in[10];
    const float* ln2_b = (const float*)d_in[11];
    const float* W1 = (const float*)d_in[12];
    const float* b1 = (const float*)d_in[13];
    const float* W2 = (const float*)d_in[14];
    const float* b2 = (const float*)d_in[15];
    float* out = (float*)d_out;

    size_t slotElems = (size_t)PAD_ROWS * DIM;
    short* s0 = (short*)d_ws;            // x (ln1) -> y (ln2)
    short* s1 = s0 + slotElems;          // q' -> h (low half; s1+s2 contiguous = h[PAD][1024])
    short* s2 = s1 + slotElems;          // t  -> h (high half)
    short* s3 = s2 + slotElems;          // res2 (bf16)
    short* mt_b  = s3 + slotElems;       // 4*128*128
    short* wov_b = mt_b + GRP * GD * GD; // 512*512
    short* w1_b  = wov_b + DIM * DIM;    // 1024*512
    short* w2_b  = w1_b + 2 * DIM * DIM; // 512*1024

    cvt_kernel<<<256, 256, 0, stream>>>(W1, w1_b, 2 * DIM * DIM);
    cvt_kernel<<<256, 256, 0, stream>>>(W2, w2_b, 2 * DIM * DIM);
    prep_m_kernel<<<GRP * GD, GD, 0, stream>>>(Wq, Wk, mt_b);
    prep_wov_kernel<<<DIM, DIM, 0, stream>>>(Wo, Wv, wov_b);

    // LN1: features -> x (bf16), zero-padded rows
    ln_kernel<<<PAD_ROWS, 128, 0, stream>>>(features, ln1_g, ln1_b, s0);

    // q' = Mt x
    qproj_kernel<<<(PAD_ROWS / 128) * 4, 256, 0, stream>>>(s0, mt_b, s1);

    // attention: gather x only -> t in s2
    attn_kernel<<<NPTS, 256, 0, stream>>>(s1, s0, neighbors, s2);

    // res2 = t @ Wov.T + bo + features  (bf16, in s3)
    outproj_kernel<<<(PAD_ROWS / 128) * 4, 256, 0, stream>>>(s2, wov_b, bo, features, s3);

    // LN2: res2 (bf16) -> y (bf16) in s0
    ln_bf16_kernel<<<PAD_ROWS, 128, 0, stream>>>(s3, ln2_g, ln2_b, s0);

    // FFN1: h = gelu(y @ W1.T + b1) -> s1..s2 region (PAD x 1024 bf16)
    ffn1_kernel<<<(PAD_ROWS / 128) * 8, 256, 0, stream>>>(s0, w1_b, b1, s1);

    // FFN2: d_out = h @ W2.T + b2 + res2
    ffn2_kernel<<<(PAD_ROWS / 128) * 4, 256, 0, stream>>>(s1, w2_b, b2, s3, out);
}